// Round 1
// baseline (388.553 us; speedup 1.0000x reference)
//
#include <hip/hip_runtime.h>
#include <stdint.h>

#define LL 1024
#define NB 8
#define EE 1024
#define HH 16
#define DD 64
#define MM (LL*NB)      // 8192 rows (l*NB+n)
#define K3 (3*EE)       // 3072

typedef __attribute__((ext_vector_type(8))) short bf16x8;   // 8 bf16 in 4 VGPRs
typedef __attribute__((ext_vector_type(4))) float f32x4;
typedef __attribute__((ext_vector_type(4))) unsigned short u16x4;
typedef __attribute__((ext_vector_type(2))) unsigned short u16x2;

__device__ __forceinline__ unsigned short f2bf(float f) {
  uint32_t u = __builtin_bit_cast(uint32_t, f);
  u += 0x7fffu + ((u >> 16) & 1u);           // RNE
  return (unsigned short)(u >> 16);
}
__device__ __forceinline__ float bf2f(unsigned short h) {
  return __builtin_bit_cast(float, ((uint32_t)h) << 16);
}
__device__ __forceinline__ f32x4 mfma16(bf16x8 a, bf16x8 b, f32x4 c) {
  return __builtin_amdgcn_mfma_f32_16x16x32_bf16(a, b, c, 0, 0, 0);
}
__device__ __forceinline__ void gload16(const unsigned short* src, unsigned short* dst) {
  __builtin_amdgcn_global_load_lds(
      (const __attribute__((address_space(1))) uint32_t*)src,
      (__attribute__((address_space(3))) uint32_t*)dst, 16, 0, 0);
}

// ---------------- fp32 -> bf16 convert ----------------
__global__ void cvt_kernel(const float* __restrict__ src, unsigned short* __restrict__ dst, int n4) {
  for (int i = blockIdx.x * blockDim.x + threadIdx.x; i < n4; i += gridDim.x * blockDim.x) {
    f32x4 v = ((const f32x4*)src)[i];
    u16x4 o;
    o[0] = f2bf(v[0]); o[1] = f2bf(v[1]); o[2] = f2bf(v[2]); o[3] = f2bf(v[3]);
    ((u16x4*)dst)[i] = o;
  }
}

// ---------------- GEMM: C[m][c] = sum_k A[m][k]*B[c][k] + bias[c] ----------------
// A: [8192][KDIM] bf16, B: [NN][KDIM] bf16 (row-major == B^T), m97-style 128x128 tile.
template<bool OUT_BF16>
__global__ __launch_bounds__(256) void gemm_bt(
    const unsigned short* __restrict__ A, const unsigned short* __restrict__ B,
    const float* __restrict__ bias, void* __restrict__ Cv, int NN, int KDIM)
{
  __shared__ __align__(16) unsigned short a_lds[128 * 32];
  __shared__ __align__(16) unsigned short b_lds[128 * 32];

  const int nwg = gridDim.x;
  const int bid = blockIdx.x;
  const int q8 = nwg >> 3;                       // nwg % 8 == 0 for all our grids
  const int swz = (bid & 7) * q8 + (bid >> 3);   // XCD-aware bijective remap
  const int brow = swz & 63;                     // 64 row tiles (column-major walk)
  const int bcol = swz >> 6;

  const int tid = threadIdx.x;
  const int w = tid >> 6, lane = tid & 63;
  const int wr = w >> 1, wc = w & 1;
  const int lrow = lane & 15, g = lane >> 4;

  f32x4 acc[4][4];
#pragma unroll
  for (int i = 0; i < 4; ++i)
#pragma unroll
    for (int j = 0; j < 4; ++j) acc[i][j] = (f32x4){0.f, 0.f, 0.f, 0.f};

  const int r_in = lane >> 2;      // 0..15 rows within a 1KB issue
  const int u = lane & 3;          // 16B unit within 64B row (BK=32 bf16)

  auto stage = [&](int kt) {
    const size_t kcol = (size_t)kt * 32 + u * 8;
    // wave w stages A issues {w, w+4} and B issues {w, w+4}; each issue = 16 rows
    gload16(A + (size_t)(brow * 128 + 16 * w + r_in) * KDIM + kcol,       &a_lds[(16 * w) * 32]);
    gload16(A + (size_t)(brow * 128 + 16 * (w + 4) + r_in) * KDIM + kcol, &a_lds[(16 * (w + 4)) * 32]);
    gload16(B + (size_t)(bcol * 128 + 16 * w + r_in) * KDIM + kcol,       &b_lds[(16 * w) * 32]);
    gload16(B + (size_t)(bcol * 128 + 16 * (w + 4) + r_in) * KDIM + kcol, &b_lds[(16 * (w + 4)) * 32]);
  };

  const int KT = KDIM >> 5;
  stage(0);
  for (int kt = 0; kt < KT; ++kt) {
    __syncthreads();               // drains vmcnt (global_load_lds) + lgkm
    bf16x8 af[4], bfr[4];
#pragma unroll
    for (int mt = 0; mt < 4; ++mt)
      af[mt] = *(const bf16x8*)&a_lds[(wr * 64 + mt * 16 + lrow) * 32 + g * 8];
#pragma unroll
    for (int nt = 0; nt < 4; ++nt)
      bfr[nt] = *(const bf16x8*)&b_lds[(wc * 64 + nt * 16 + lrow) * 32 + g * 8];
#pragma unroll
    for (int mt = 0; mt < 4; ++mt)
#pragma unroll
      for (int nt = 0; nt < 4; ++nt)
        acc[mt][nt] = mfma16(af[mt], bfr[nt], acc[mt][nt]);
    __syncthreads();
    if (kt + 1 < KT) stage(kt + 1);
  }

  // epilogue: C layout col = lane&15, row = (lane>>4)*4 + j
#pragma unroll
  for (int nt = 0; nt < 4; ++nt) {
    const int c = bcol * 128 + wc * 64 + nt * 16 + lrow;
    const float bv = bias ? bias[c] : 0.f;
#pragma unroll
    for (int mt = 0; mt < 4; ++mt) {
      const int m0 = brow * 128 + wr * 64 + mt * 16 + g * 4;
#pragma unroll
      for (int j = 0; j < 4; ++j) {
        const float v = acc[mt][nt][j] + bv;
        if (OUT_BF16) ((unsigned short*)Cv)[(size_t)(m0 + j) * NN + c] = f2bf(v);
        else          ((float*)Cv)[(size_t)(m0 + j) * NN + c] = v;
      }
    }
  }
}

// ---------------- V transpose: stack v cols -> vt[n][h][d][s] ----------------
__global__ void transpose_v(const unsigned short* __restrict__ stack, unsigned short* __restrict__ vt) {
  __shared__ __align__(16) unsigned short tile[64][68];
  const int b = blockIdx.x;                 // 8*16*16 = 2048
  const int lchunk = b & 15, h = (b >> 4) & 15, n = b >> 8;
  const int t = threadIdx.x;
  const int c4 = (t & 15) * 4, r = t >> 4;  // r 0..15
#pragma unroll
  for (int p = 0; p < 4; ++p) {
    const int l = lchunk * 64 + p * 16 + r;
    u16x4 v = *(const u16x4*)&stack[(size_t)(l * NB + n) * K3 + 2 * EE + h * DD + c4];
    *(u16x4*)&tile[p * 16 + r][c4] = v;
  }
  __syncthreads();
#pragma unroll
  for (int p = 0; p < 4; ++p) {
    const int d = p * 16 + r;
    u16x4 o;
#pragma unroll
    for (int i = 0; i < 4; ++i) o[i] = tile[c4 + i][d];
    *(u16x4*)&vt[((size_t)(n * HH + h) * DD + d) * LL + lchunk * 64 + c4] = o;
  }
}

// ---------------- fused attention ----------------
// grid 512 = n(8) x l-tile(64 of 16 rows); block 512 = 8 waves, wave w owns s in [w*128, w*128+128)
__global__ __launch_bounds__(512) void attn_fused(
    const unsigned short* __restrict__ stack,  // [8192][3072]: q | k | v
    const unsigned short* __restrict__ vt,     // [n][h][d][1024]
    unsigned short* __restrict__ ctxo,         // [8192][1024] bf16
    float* __restrict__ attn_out)              // [n][1024][1024]
{
  __shared__ float red_max[8][16];
  __shared__ float red_sum[8][16];
  __shared__ __align__(16) unsigned short ctx_red[8][16][72];  // [wave][l][d] bf16 partial ctx
  __shared__ __align__(16) unsigned short p_lds[8][16][136];   // [wave][l][s_local] bf16 P

  const int bid = blockIdx.x;
  const int swz = (bid & 7) * 64 + (bid >> 3);   // XCD: one n per XCD
  const int n = swz >> 6;
  const int lt = (swz & 63) << 4;
  const int tid = threadIdx.x;
  const int w = tid >> 6, lane = tid & 63;
  const int ll = lane & 15, g = lane >> 4;
  const int sbase = w << 7;
  const int lrow = lt + ll;

  f32x4 attn_acc[8];
#pragma unroll
  for (int i = 0; i < 8; ++i) attn_acc[i] = (f32x4){0.f, 0.f, 0.f, 0.f};

  const unsigned short* qbase = stack + (size_t)(lrow * NB + n) * K3;

  for (int h = 0; h < HH; ++h) {
    // ---- S^T = K . Q^T  (i = s, j = l): lane holds one q-row's column slice ----
    const bf16x8 qf0 = *(const bf16x8*)(qbase + h * DD + g * 8);
    const bf16x8 qf1 = *(const bf16x8*)(qbase + h * DD + 32 + g * 8);
    f32x4 sc[8];
#pragma unroll
    for (int st = 0; st < 8; ++st) {
      sc[st] = (f32x4){0.f, 0.f, 0.f, 0.f};
      const int s = sbase + st * 16 + ll;
      const unsigned short* kp = stack + (size_t)(s * NB + n) * K3 + EE + h * DD + g * 8;
      const bf16x8 kf0 = *(const bf16x8*)kp;
      const bf16x8 kf1 = *(const bf16x8*)(kp + 32);
      sc[st] = mfma16(kf0, qf0, sc[st]);
      sc[st] = mfma16(kf1, qf1, sc[st]);
    }
    // ---- softmax over s (per q-row l = lt+ll) ----
    float mx = -3.0e38f;
#pragma unroll
    for (int st = 0; st < 8; ++st) {
      sc[st] *= 0.125f;
#pragma unroll
      for (int j = 0; j < 4; ++j) mx = fmaxf(mx, sc[st][j]);
    }
    mx = fmaxf(mx, __shfl_xor(mx, 16));
    mx = fmaxf(mx, __shfl_xor(mx, 32));
    if (lane < 16) red_max[w][lane] = mx;
    __syncthreads();
    mx = red_max[0][ll];
#pragma unroll
    for (int r = 1; r < 8; ++r) mx = fmaxf(mx, red_max[r][ll]);

    float sum = 0.f;
#pragma unroll
    for (int st = 0; st < 8; ++st)
#pragma unroll
      for (int j = 0; j < 4; ++j) { const float e = __expf(sc[st][j] - mx); sc[st][j] = e; sum += e; }
    sum += __shfl_xor(sum, 16);
    sum += __shfl_xor(sum, 32);
    if (lane < 16) red_sum[w][lane] = sum;
    __syncthreads();
    sum = red_sum[0][ll];
#pragma unroll
    for (int r = 1; r < 8; ++r) sum += red_sum[r][ll];
    const float rinv = 1.0f / sum;
    const float rH = rinv * (1.0f / 16.0f);

    // ---- attention-mean accumulate + stage P (normalized, bf16) ----
#pragma unroll
    for (int st = 0; st < 8; ++st) {
      attn_acc[st] += sc[st] * rH;
      u16x4 pw;
#pragma unroll
      for (int j = 0; j < 4; ++j) pw[j] = f2bf(sc[st][j] * rinv);
      *(u16x4*)&p_lds[w][ll][st * 16 + g * 4] = pw;
    }
    // ---- context^T = V^T . P^T  (i = d, j = l), partial over this wave's s-range ----
    bf16x8 pf[4];
#pragma unroll
    for (int ks = 0; ks < 4; ++ks) pf[ks] = *(const bf16x8*)&p_lds[w][ll][ks * 32 + g * 8];
    const unsigned short* vbase = vt + (size_t)(n * HH + h) * DD * LL + sbase + g * 8;
#pragma unroll
    for (int dt = 0; dt < 4; ++dt) {
      f32x4 cc = (f32x4){0.f, 0.f, 0.f, 0.f};
      const unsigned short* vp = vbase + (size_t)(dt * 16 + ll) * LL;
#pragma unroll
      for (int ks = 0; ks < 4; ++ks) {
        const bf16x8 vf = *(const bf16x8*)(vp + ks * 32);
        cc = mfma16(vf, pf[ks], cc);
      }
      u16x4 cw;
#pragma unroll
      for (int j = 0; j < 4; ++j) cw[j] = f2bf(cc[j]);
      *(u16x4*)&ctx_red[w][ll][dt * 16 + g * 4] = cw;
    }
    __syncthreads();
    // ---- reduce partial contexts over 8 waves, store bf16 ----
    {
      const int l2 = tid >> 5;
      const int d2 = (tid & 31) * 2;
      float s0 = 0.f, s1 = 0.f;
#pragma unroll
      for (int r = 0; r < 8; ++r) {
        u16x2 v = *(const u16x2*)&ctx_red[r][l2][d2];
        s0 += bf2f(v[0]); s1 += bf2f(v[1]);
      }
      u16x2 o; o[0] = f2bf(s0); o[1] = f2bf(s1);
      *(u16x2*)&ctxo[(size_t)((lt + l2) * NB + n) * EE + h * DD + d2] = o;
    }
    __syncthreads();
  }
  // ---- write attention-mean output ----
  float* ap = attn_out + ((size_t)n * LL + lt + ll) * LL + sbase;
#pragma unroll
  for (int st = 0; st < 8; ++st) *(f32x4*)(ap + st * 16 + g * 4) = attn_acc[st];
}

extern "C" void kernel_launch(void* const* d_in, const int* in_sizes, int n_in,
                              void* d_out, int out_size, void* d_ws, size_t ws_size,
                              hipStream_t stream) {
  const float* x   = (const float*)d_in[0];
  const float* win = (const float*)d_in[1];
  const float* bin = (const float*)d_in[2];
  const float* ow  = (const float*)d_in[3];
  const float* ob  = (const float*)d_in[4];
  float* out = (float*)d_out;

  const size_t need = ((size_t)MM * EE + (size_t)K3 * EE + (size_t)EE * EE +
                       (size_t)MM * K3 + (size_t)NB * HH * DD * LL) * 2;
  if (ws_size < need) return;  // fail loudly via validation rather than corrupt memory

  unsigned short* ws    = (unsigned short*)d_ws;
  unsigned short* xb    = ws;                        // [8192][1024]
  unsigned short* wb    = xb + (size_t)MM * EE;      // [3072][1024]
  unsigned short* owb   = wb + (size_t)K3 * EE;      // [1024][1024]
  unsigned short* stack = owb + (size_t)EE * EE;     // [8192][3072]
  unsigned short* vt    = stack + (size_t)MM * K3;   // [8][16][64][1024]
  unsigned short* ctx   = xb;                        // reuse x region after GEMM1

  cvt_kernel<<<2048, 256, 0, stream>>>(x, xb, (MM * EE) / 4);
  cvt_kernel<<<1024, 256, 0, stream>>>(win, wb, (K3 * EE) / 4);
  cvt_kernel<<<512, 256, 0, stream>>>(ow, owb, (EE * EE) / 4);
  gemm_bt<true><<<64 * (K3 / 128), 256, 0, stream>>>(xb, wb, bin, stack, K3, EE);
  transpose_v<<<2048, 256, 0, stream>>>(stack, vt);
  attn_fused<<<512, 512, 0, stream>>>(stack, vt, ctx, out + (size_t)MM * EE);
  gemm_bt<false><<<64 * (EE / 128), 256, 0, stream>>>(ctx, owb, ob, out, EE, EE);
}